// Round 1
// baseline (771.737 us; speedup 1.0000x reference)
//
#include <hip/hip_runtime.h>
#include <hip/hip_bf16.h>
#include <cstdint>

// ---------------------------------------------------------------------------
// B=2, S=4096, D=512, H=8, HD=64.
// prep: fused xcvt (X fp32 -> bf16 proj image) + wt (W -> W^T bf16 image).
// proj: unchanged all-bf16 128x128-tile GEMM, DMA-staged, XCD-pinned.
// attn: restructured for max occupancy: 1024-thread blocks (16 waves =
//       4 wq x 4 kh), same 64KB double-buffered K/V tile shared by twice the
//       waves -> 2 blocks/CU x 1024 thr = 2048 thr/CU (32 waves, was 16).
//       Each wave does ONE 32x32 kg per iteration (kh 4-way k-split, pairwise
//       combined in epilogue). l-sum via v_dot2_f32_f16 on packed P pairs.
//       s_setprio(1) around MFMA clusters.
// ---------------------------------------------------------------------------

typedef __bf16   bf16x8 __attribute__((ext_vector_type(8)));
typedef _Float16 f16x8  __attribute__((ext_vector_type(8)));
typedef _Float16 f16x2  __attribute__((ext_vector_type(2)));
typedef float    f32x4  __attribute__((ext_vector_type(4)));
typedef float    f32x16 __attribute__((ext_vector_type(16)));
typedef unsigned int   u32;
typedef unsigned int   u32x4 __attribute__((ext_vector_type(4)));
typedef unsigned short u16;

#define NB  2
#define SEQ 4096
#define DIM 512
#define NH  8
#define HD  64
#define WSZ (DIM * DIM)
#define XSZ (NB * SEQ * DIM)
#define QSZ (NB * NH * SEQ * HD)

#if __has_builtin(__builtin_amdgcn_fdot2)
#define HAVE_FDOT2 1
#else
#define HAVE_FDOT2 0
#endif

__device__ __forceinline__ u16 f2bf(float f) {
    __bf16 h = (__bf16)f; return __builtin_bit_cast(u16, h);
}
__device__ __forceinline__ u16 f2h(float f) {
    _Float16 h = (_Float16)f; return __builtin_bit_cast(u16, h);
}
__device__ __forceinline__ u32 pack_pkrtz(float a, float b) {
    auto pk = __builtin_amdgcn_cvt_pkrtz(a, b);
    return __builtin_bit_cast(u32, pk);
}
__device__ __forceinline__ bf16x8 cvt8p(float4 a, float4 b) {
    bf16x8 o;
    o[0]=(__bf16)a.x; o[1]=(__bf16)a.y; o[2]=(__bf16)a.z; o[3]=(__bf16)a.w;
    o[4]=(__bf16)b.x; o[5]=(__bf16)b.y; o[6]=(__bf16)b.z; o[7]=(__bf16)b.w;
    return o;
}
__device__ __forceinline__ void dma16(const u16* g, u16* l) {
    __builtin_amdgcn_global_load_lds(
        (const __attribute__((address_space(1))) u32*)g,
        (__attribute__((address_space(3))) u32*)l, 16, 0, 0);
}

// --- prep: fused xcvt + wt ---------------------------------------------------
// blocks [0,3072): xcvt  (id = p*1024 + mtile*16 + kslab ; 128x32 slab)
// blocks [3072,3264): wt (id2 = p*64 + r*8 + c)
__global__ __launch_bounds__(256) void prep_kernel(
    const float* __restrict__ xq, const float* __restrict__ xk,
    const float* __restrict__ xv,
    const float* __restrict__ Wq, const float* __restrict__ Wk,
    const float* __restrict__ Wv,
    u16* __restrict__ xb, u16* __restrict__ wtImg)
{
    __shared__ u16 lT[64 * 65];
    const int id = blockIdx.x;
    const int t = threadIdx.x;
    if (id < 3072) {
        const int p = id >> 10, rest = id & 1023;
        const int mtile = rest >> 4, kk = rest & 15;
        const float* X = (p == 0) ? xq : ((p == 1) ? xk : xv);
        const int row = t >> 1, half = t & 1;
        const float* src = X + ((size_t)(mtile * 128 + row)) * DIM + kk * 32 + half * 16;
        u16* dst = xb + (size_t)p * XSZ + ((size_t)(mtile * 16 + kk)) * 4096 + row * 32;
        const int sr = (row ^ (row >> 2)) & 3;
        float4 a0 = ((const float4*)src)[0], a1 = ((const float4*)src)[1];
        float4 a2 = ((const float4*)src)[2], a3 = ((const float4*)src)[3];
        const int c0 = (half * 2) ^ sr, c1 = (half * 2 + 1) ^ sr;
        *(bf16x8*)(dst + (c0 << 3)) = cvt8p(a0, a1);
        *(bf16x8*)(dst + (c1 << 3)) = cvt8p(a2, a3);
    } else {
        const int id2 = id - 3072;
        const int p = id2 >> 6;
        const float* W = (p == 0) ? Wq : ((p == 1) ? Wk : Wv);
        const int r0 = ((id2 >> 3) & 7) * 64, c0 = (id2 & 7) * 64;
#pragma unroll
        for (int i = 0; i < 16; i++) {
            int idx = i * 256 + t, rowk = idx >> 6, coln = idx & 63;
            lT[coln * 65 + rowk] = f2bf(W[(size_t)(r0 + rowk) * DIM + c0 + coln]);
        }
        __syncthreads();
#pragma unroll
        for (int i = 0; i < 2; i++) {
            const int idx = i * 256 + t;           // 0..511
            const int nl = idx >> 3, ch = idx & 7;
            const int n = c0 + nl;
            const int row = n & 127, ntile = n >> 7;
            const int kk = (r0 >> 5) + (ch >> 2);
            const int sw = (ch & 3) ^ ((row ^ (row >> 2)) & 3);
            u16* d = wtImg + (size_t)p * WSZ + ((size_t)(ntile * 16 + kk)) * 4096
                   + row * 32 + (sw << 3);
#pragma unroll
            for (int e = 0; e < 8; e++) d[e] = lT[nl * 65 + ch * 8 + e];
        }
    }
}

// --- proj: all-bf16, DMA-staged, XCD-pinned (unchanged) ----------------------
__global__ __launch_bounds__(256) void proj_kernel(
    const u16* __restrict__ xb, const u16* __restrict__ wtImg,
    const float* __restrict__ bq, const float* __restrict__ bk,
    const float* __restrict__ bv,
    u16* __restrict__ qb, u16* __restrict__ kbImg, u16* __restrict__ vtImg)
{
    __shared__ u16 smem[16384];   // 2 x (A 4096 | B 4096); epilogue: 128x128 tile

    const int tid = threadIdx.x;
    const int wave = tid >> 6, lane = tid & 63;
    const int l16 = lane & 15, quad = lane >> 4;
    const int wq = wave >> 1, wn = wave & 1;

    const int id = blockIdx.x;
    const int xcd = id & 7, j = id >> 3;
    const int p = j >> 5, t5 = j & 31;
    int mb, nb;
    if (p < 2) { mb = xcd * 8 + (t5 >> 2); nb = t5 & 3; }
    else       { nb = xcd * 8 + (t5 >> 2); mb = t5 & 3; }

    const u16* Abase = (p < 2) ? xb + (size_t)p * XSZ + (size_t)mb * 16 * 4096
                               : wtImg + (size_t)2 * WSZ + (size_t)mb * 16 * 4096;
    const u16* Bbase = (p < 2) ? wtImg + (size_t)p * WSZ + (size_t)nb * 16 * 4096
                               : xb + (size_t)2 * XSZ + (size_t)nb * 16 * 4096;
    const int doff = tid * 8;   // u16 units; 16B per thread per dma

    f32x4 acc[4][4];
#pragma unroll
    for (int ms = 0; ms < 4; ms++)
#pragma unroll
        for (int ns = 0; ns < 4; ns++)
#pragma unroll
            for (int jj = 0; jj < 4; jj++) acc[ms][ns][jj] = 0.f;

#pragma unroll
    for (int e = 0; e < 2; e++) {
        dma16(Abase + e * 2048 + doff, smem + e * 2048 + doff);
        dma16(Bbase + e * 2048 + doff, smem + 4096 + e * 2048 + doff);
    }
    Abase += 4096; Bbase += 4096;

    for (int kt = 0; kt < 16; kt++) {
        __syncthreads();
        if (kt < 15) {
            u16* lb = smem + ((kt + 1) & 1) * 8192;
#pragma unroll
            for (int e = 0; e < 2; e++) {
                dma16(Abase + e * 2048 + doff, lb + e * 2048 + doff);
                dma16(Bbase + e * 2048 + doff, lb + 4096 + e * 2048 + doff);
            }
            Abase += 4096; Bbase += 4096;
        }
        const u16* lA = smem + (kt & 1) * 8192;
        const u16* lB = lA + 4096;

        bf16x8 af[4];
#pragma unroll
        for (int ms = 0; ms < 4; ms++) {
            const int row = wq * 64 + ms * 16 + l16;
            const int sr = (row ^ (row >> 2)) & 3;
            af[ms] = *(const bf16x8*)&lA[row * 32 + ((quad ^ sr) << 3)];
        }
#pragma unroll
        for (int ns = 0; ns < 4; ns++) {
            const int rowb = wn * 64 + ns * 16 + l16;
            const int sb = (rowb ^ (rowb >> 2)) & 3;
            const bf16x8 b = *(const bf16x8*)&lB[rowb * 32 + ((quad ^ sb) << 3)];
#pragma unroll
            for (int ms = 0; ms < 4; ms++)
                acc[ms][ns] = __builtin_amdgcn_mfma_f32_16x16x32_bf16(af[ms], b, acc[ms][ns], 0, 0, 0);
        }
    }

    __syncthreads();
    if (p < 2) {
        const float* bias = p ? bk : bq;
        const float cs = (p == 0) ? 0.18033688011112042f : 1.0f;   // log2e/8
        const int stl = wn * 2 + wq;
        const int hh = nb * 2 + wn;
#pragma unroll
        for (int ns = 0; ns < 4; ns++) {
            const int ch = ns * 16 + l16;
            const float bval = bias[hh * 64 + ch];
#pragma unroll
            for (int ms = 0; ms < 4; ms++)
#pragma unroll
                for (int rr = 0; rr < 4; rr++) {
                    const int sqL = ms * 16 + quad * 4 + rr;
                    const float v = (acc[ms][ns][rr] + bval) * cs;
                    int off;
                    if (p == 0) off = sqL * 64 + ch;
                    else        off = sqL * 64 +
                                      (((ch >> 3) ^ ((sqL ^ (sqL >> 3)) & 7)) << 3) + (ch & 7);
                    smem[stl * 4096 + off] = f2bf(v);
                }
        }
    } else {
        const int stl = wq * 2 + wn;
#pragma unroll
        for (int ms = 0; ms < 4; ms++)
#pragma unroll
            for (int rr = 0; rr < 4; rr++) {
                const int hd = ms * 16 + quad * 4 + rr;
                const float bval = bv[mb * 128 + wq * 64 + hd];
                const int swh = (hd ^ (hd >> 3)) & 7;
#pragma unroll
                for (int ns = 0; ns < 4; ns++) {
                    const int nl = ns * 16 + l16;
                    const int sqpL = (nl & ~12) | ((nl & 8) >> 1) | ((nl & 4) << 1);
                    smem[stl * 4096 + hd * 64 +
                         (((sqpL >> 3) ^ swh) << 3) + (sqpL & 7)] =
                        f2h(acc[ms][ns][rr] + bval);
                }
            }
    }
    __syncthreads();

    {
        u16* dstp; size_t gbase;
        if (p < 2) {
            const int hh = nb * 2 + (wave >> 1);
            const int b2 = mb >> 5;
            const int row0 = (mb * 128 + (wave & 1) * 64) & 4095;
            if (p == 0) { dstp = qb;    gbase = ((size_t)(b2 * NH + hh) * 4096 + row0) * 64; }
            else        { dstp = kbImg; gbase = ((size_t)((b2 * NH + hh) * 64 + (row0 >> 6))) * 4096; }
        } else {
            const int hh = mb * 2 + (wave >> 1);
            const int b2 = nb >> 5;
            const int nblk = (nb & 31) * 2 + (wave & 1);
            dstp = vtImg; gbase = ((size_t)((b2 * NH + hh) * 64 + nblk)) * 4096;
        }
#pragma unroll
        for (int e = 0; e < 8; e++) {
            const u32x4 vv = *(const u32x4*)&smem[wave * 4096 + e * 512 + lane * 8];
            *(u32x4*)(dstp + gbase + e * 512 + lane * 8) = vv;
        }
    }
}

// --- flash attention: 1024 threads, 4 wq x 4 kh, DMA double-buffer ----------
// Per it: block stages 128 contiguous k rows (chunks 2it,2it+1) of K and V
// (32KB/buffer, 64KB dbuf). kh splits the 128 rows 4 ways (32 each).
__global__ __launch_bounds__(1024, 8) void attn_kernel(
    const u16* __restrict__ qb, const u16* __restrict__ kbImg,
    const u16* __restrict__ vtImg, float* __restrict__ out)
{
    __shared__ u16 smem[2 * 16384];   // [buf][K 8192 | V 8192] u16 = 64KB
    float* sf = (float*)smem;

    const int tid = threadIdx.x;
    const int wave = tid >> 6, lane = tid & 63;
    const int m31 = lane & 31, h = lane >> 5;
    const int wq = wave >> 2, kh = wave & 3;

    const int blk = blockIdx.x;
    const int xcd = blk & 7, idx = blk >> 3;
    const int bh = xcd * 2 + (idx >> 5);
    const int qt = idx & 31;
    const int qbase = qt * 128 + wq * 32;

    bf16x8 qF[4];
#pragma unroll
    for (int c = 0; c < 4; c++)
        qF[c] = *(const bf16x8*)(qb + ((size_t)bh * SEQ + qbase + m31) * HD + c * 16 + h * 8);

    f32x16 O0, O1;
#pragma unroll
    for (int j = 0; j < 16; j++) { O0[j] = 0.f; O1[j] = 0.f; }
    float la_ = 0.f, lb_ = 0.f;
#if HAVE_FDOT2
    const f16x2 one2 = {(_Float16)1.f, (_Float16)1.f};
#endif

    // staging: 16 waves; waves 0-7 stage K (2 chunks = 16KB), 8-15 stage V.
    const int region = wave >> 3, sub8 = wave & 7;
    const u16* img = region ? vtImg : kbImg;
    const u16* gp = img + ((size_t)(bh * 64)) * 4096 + sub8 * 1024 + lane * 8;
    u16* const lds0 = smem + region * 8192 + sub8 * 1024 + lane * 8;

    dma16(gp, lds0); dma16(gp + 512, lds0 + 512);
    gp += 8192;

    const int NT = 32;
    for (int it = 0; it < NT; it++) {
        __syncthreads();
        if (it + 1 < NT) {
            u16* ld = lds0 + ((it + 1) & 1) * 16384;
            dma16(gp, ld); dma16(gp + 512, ld + 512);
            gp += 8192;
        }
        const u16* sb = smem + (it & 1) * 16384;
        const u16* sK = sb + ((kh >> 1) << 12);
        const u16* sV = sb + 8192 + ((kh >> 1) << 12);

        // K fragment: rows (kh&1)*32 + m31 of chunk (kh>>1)
        const int rK = ((kh & 1) << 5) + m31;
        const int swK = (rK ^ (rK >> 3)) & 7;
        bf16x8 kA[4];
#pragma unroll
        for (int c = 0; c < 4; c++)
            kA[c] = *(const bf16x8*)&sK[(rK << 6) + (((2 * c + h) ^ swK) << 3)];

        f32x16 Sv;
#pragma unroll
        for (int j = 0; j < 16; j++) Sv[j] = 0.f;
        __builtin_amdgcn_s_setprio(1);
#pragma unroll
        for (int c = 0; c < 4; c++)
            Sv = __builtin_amdgcn_mfma_f32_32x32x16_bf16(kA[c], qF[c], Sv, 0, 0, 0);
        __builtin_amdgcn_s_setprio(0);

        // V fragments: seq cols (kh&1)*32.. of chunk (kh>>1)
        const int gb = (kh & 1) << 2;
        const int swV0 = (m31 ^ (m31 >> 3)) & 7;
        const int rV1 = 32 + m31;
        const int swV1 = (rV1 ^ (rV1 >> 3)) & 7;
        f16x8 vA0[2], vA1[2];
#pragma unroll
        for (int c2 = 0; c2 < 2; c2++) {
            vA0[c2] = *(const f16x8*)&sV[(m31 << 6) + (((gb + 2 * c2 + h) ^ swV0) << 3)];
            vA1[c2] = *(const f16x8*)&sV[(rV1 << 6) + (((gb + 2 * c2 + h) ^ swV1) << 3)];
        }

        u32 P32[8];
#pragma unroll
        for (int mm = 0; mm < 8; mm++) {
            const float ea = __builtin_amdgcn_exp2f(Sv[2 * mm]);
            const float eb = __builtin_amdgcn_exp2f(Sv[2 * mm + 1]);
            P32[mm] = pack_pkrtz(ea, eb);
#if HAVE_FDOT2
            const f16x2 pp = __builtin_bit_cast(f16x2, P32[mm]);
            if (mm & 1) lb_ = __builtin_amdgcn_fdot2(pp, one2, lb_, false);
            else        la_ = __builtin_amdgcn_fdot2(pp, one2, la_, false);
#else
            if (mm & 1) lb_ += ea + eb; else la_ += ea + eb;
#endif
        }

        u32x4 f0, f1;
        f0[0] = P32[0]; f0[1] = P32[1]; f0[2] = P32[2]; f0[3] = P32[3];
        f1[0] = P32[4]; f1[1] = P32[5]; f1[2] = P32[6]; f1[3] = P32[7];
        const f16x8 pf0 = __builtin_bit_cast(f16x8, f0);
        const f16x8 pf1 = __builtin_bit_cast(f16x8, f1);
        __builtin_amdgcn_s_setprio(1);
        O0 = __builtin_amdgcn_mfma_f32_32x32x16_f16(vA0[0], pf0, O0, 0, 0, 0);
        O0 = __builtin_amdgcn_mfma_f32_32x32x16_f16(vA0[1], pf1, O0, 0, 0, 0);
        O1 = __builtin_amdgcn_mfma_f32_32x32x16_f16(vA1[0], pf0, O1, 0, 0, 0);
        O1 = __builtin_amdgcn_mfma_f32_32x32x16_f16(vA1[1], pf1, O1, 0, 0, 0);
        __builtin_amdgcn_s_setprio(0);
    }

    // ---- epilogue: combine 4 kh partials --------------------------------
    float l_acc = la_ + lb_;
    l_acc += __shfl_xor(l_acc, 32);

    // l combine: 16 waves x 32 q = 2KB (buf0 area, not in use after last it)
    if (lane < 32) sf[wave * 32 + lane] = l_acc;
    __syncthreads();
    const float lt = sf[(wq * 4 + 0) * 32 + m31] + sf[(wq * 4 + 1) * 32 + m31]
                   + sf[(wq * 4 + 2) * 32 + m31] + sf[(wq * 4 + 3) * 32 + m31];
    const float inv = 1.0f / lt;
    __syncthreads();

    // Round 1: kh 2,3 dump partials (8 waves x 8KB = 64KB)
    if (kh >= 2) {
        const int w2 = wq * 2 + (kh - 2);
#pragma unroll
        for (int s = 0; s < 8; s++) {
            f32x4 tv;
#pragma unroll
            for (int j = 0; j < 4; j++) tv[j] = (s < 4 ? O0 : O1)[(s & 3) * 4 + j];
            *(f32x4*)&sf[w2 * 2048 + s * 256 + lane * 4] = tv;
        }
    }
    __syncthreads();
    if (kh < 2) {
        const int w2 = wq * 2 + kh;
#pragma unroll
        for (int s = 0; s < 8; s++) {
            const f32x4 tv = *(const f32x4*)&sf[w2 * 2048 + s * 256 + lane * 4];
#pragma unroll
            for (int j = 0; j < 4; j++) {
                if (s < 4) O0[(s & 3) * 4 + j] += tv[j];
                else       O1[(s & 3) * 4 + j] += tv[j];
            }
        }
    }
    __syncthreads();
    // Round 2: kh 1 dumps (4 waves x 8KB = 32KB)
    if (kh == 1) {
#pragma unroll
        for (int s = 0; s < 8; s++) {
            f32x4 tv;
#pragma unroll
            for (int j = 0; j < 4; j++) tv[j] = (s < 4 ? O0 : O1)[(s & 3) * 4 + j];
            *(f32x4*)&sf[wq * 2048 + s * 256 + lane * 4] = tv;
        }
    }
    __syncthreads();
    if (kh == 0) {
        const int b = bh >> 3, hcol = bh & 7;
        const int sq = qbase + m31;
#pragma unroll
        for (int hg = 0; hg < 2; hg++)
#pragma unroll
            for (int mm = 0; mm < 4; mm++) {
                const int s = hg * 4 + mm;
                const f32x4 po = *(const f32x4*)&sf[wq * 2048 + s * 256 + lane * 4];
                f32x4 o;
#pragma unroll
                for (int j = 0; j < 4; j++)
                    o[j] = ((hg ? O1 : O0)[4 * mm + j] + po[j]) * inv;
                *(f32x4*)&out[(((size_t)(b * SEQ + sq)) << 9) + hcol * 64
                              + hg * 32 + 8 * mm + 4 * h] = o;
            }
    }
}

// ---------------------------------------------------------------------------
extern "C" void kernel_launch(void* const* d_in, const int* in_sizes, int n_in,
                              void* d_out, int out_size, void* d_ws, size_t ws_size,
                              hipStream_t stream)
{
    const float* q  = (const float*)d_in[0];
    const float* k  = (const float*)d_in[1];
    const float* v  = (const float*)d_in[2];
    const float* Wq = (const float*)d_in[3];
    const float* bq = (const float*)d_in[4];
    const float* Wk = (const float*)d_in[5];
    const float* bk = (const float*)d_in[6];
    const float* Wv = (const float*)d_in[7];
    const float* bv = (const float*)d_in[8];
    float* out = (float*)d_out;

    // ws layout (u16): xb[3*XSZ] | wtImg[3*WSZ] | qb[QSZ] | kbImg[QSZ] | vtImg[QSZ]
    u16* xb  = (u16*)d_ws;
    u16* wti = xb  + (size_t)3 * XSZ;
    u16* qbp = wti + (size_t)3 * WSZ;
    u16* kbp = qbp + (size_t)QSZ;
    u16* vtp = kbp + (size_t)QSZ;

    prep_kernel<<<dim3(3264), 256, 0, stream>>>(q, k, v, Wq, Wk, Wv, xb, wti);
    proj_kernel<<<dim3(768),  256, 0, stream>>>(xb, wti, bq, bk, bv,
                                                qbp, kbp, vtp);
    attn_kernel<<<dim3(512), 1024, 0, stream>>>(qbp, kbp, vtp, out);
}

// Round 2
// 202.516 us; speedup vs baseline: 3.8107x; 3.8107x over previous
//
#include <hip/hip_runtime.h>
#include <hip/hip_bf16.h>
#include <cstdint>

// ---------------------------------------------------------------------------
// B=2, S=4096, D=512, H=8, HD=64.
// prep: fused xcvt (X fp32 -> bf16 proj image) + wt (W -> W^T bf16 image).
// proj: all-bf16 128x128-tile GEMM, DMA-staged, XCD-pinned.
// attn: round-0 shape (512 thr, 4wq x 2kh, 64KB dbuf, 2 blocks/CU) with a
//       software-pipelined inner iteration:
//         QK(kg0) -> exp(kg0) -> {QK(kg1) 1:1 PV(kg0)} -> exp(kg1) -> PV(kg1)
//       3 independent MFMA chains in the middle phase; l-sum via fdot2;
//       s_setprio(1) around MFMA clusters. Per-wave regs ~114 < 128 cap.
// ---------------------------------------------------------------------------

typedef __bf16   bf16x8 __attribute__((ext_vector_type(8)));
typedef _Float16 f16x8  __attribute__((ext_vector_type(8)));
typedef _Float16 f16x2  __attribute__((ext_vector_type(2)));
typedef float    f32x4  __attribute__((ext_vector_type(4)));
typedef float    f32x16 __attribute__((ext_vector_type(16)));
typedef unsigned int   u32;
typedef unsigned int   u32x4 __attribute__((ext_vector_type(4)));
typedef unsigned short u16;

#define NB  2
#define SEQ 4096
#define DIM 512
#define NH  8
#define HD  64
#define WSZ (DIM * DIM)
#define XSZ (NB * SEQ * DIM)
#define QSZ (NB * NH * SEQ * HD)

#if __has_builtin(__builtin_amdgcn_fdot2)
#define HAVE_FDOT2 1
#else
#define HAVE_FDOT2 0
#endif

__device__ __forceinline__ u16 f2bf(float f) {
    __bf16 h = (__bf16)f; return __builtin_bit_cast(u16, h);
}
__device__ __forceinline__ u16 f2h(float f) {
    _Float16 h = (_Float16)f; return __builtin_bit_cast(u16, h);
}
__device__ __forceinline__ u32 pack_pkrtz(float a, float b) {
    auto pk = __builtin_amdgcn_cvt_pkrtz(a, b);
    return __builtin_bit_cast(u32, pk);
}
__device__ __forceinline__ bf16x8 cvt8p(float4 a, float4 b) {
    bf16x8 o;
    o[0]=(__bf16)a.x; o[1]=(__bf16)a.y; o[2]=(__bf16)a.z; o[3]=(__bf16)a.w;
    o[4]=(__bf16)b.x; o[5]=(__bf16)b.y; o[6]=(__bf16)b.z; o[7]=(__bf16)b.w;
    return o;
}
__device__ __forceinline__ void dma16(const u16* g, u16* l) {
    __builtin_amdgcn_global_load_lds(
        (const __attribute__((address_space(1))) u32*)g,
        (__attribute__((address_space(3))) u32*)l, 16, 0, 0);
}

// --- prep: fused xcvt + wt ---------------------------------------------------
__global__ __launch_bounds__(256) void prep_kernel(
    const float* __restrict__ xq, const float* __restrict__ xk,
    const float* __restrict__ xv,
    const float* __restrict__ Wq, const float* __restrict__ Wk,
    const float* __restrict__ Wv,
    u16* __restrict__ xb, u16* __restrict__ wtImg)
{
    __shared__ u16 lT[64 * 65];
    const int id = blockIdx.x;
    const int t = threadIdx.x;
    if (id < 3072) {
        const int p = id >> 10, rest = id & 1023;
        const int mtile = rest >> 4, kk = rest & 15;
        const float* X = (p == 0) ? xq : ((p == 1) ? xk : xv);
        const int row = t >> 1, half = t & 1;
        const float* src = X + ((size_t)(mtile * 128 + row)) * DIM + kk * 32 + half * 16;
        u16* dst = xb + (size_t)p * XSZ + ((size_t)(mtile * 16 + kk)) * 4096 + row * 32;
        const int sr = (row ^ (row >> 2)) & 3;
        float4 a0 = ((const float4*)src)[0], a1 = ((const float4*)src)[1];
        float4 a2 = ((const float4*)src)[2], a3 = ((const float4*)src)[3];
        const int c0 = (half * 2) ^ sr, c1 = (half * 2 + 1) ^ sr;
        *(bf16x8*)(dst + (c0 << 3)) = cvt8p(a0, a1);
        *(bf16x8*)(dst + (c1 << 3)) = cvt8p(a2, a3);
    } else {
        const int id2 = id - 3072;
        const int p = id2 >> 6;
        const float* W = (p == 0) ? Wq : ((p == 1) ? Wk : Wv);
        const int r0 = ((id2 >> 3) & 7) * 64, c0 = (id2 & 7) * 64;
#pragma unroll
        for (int i = 0; i < 16; i++) {
            int idx = i * 256 + t, rowk = idx >> 6, coln = idx & 63;
            lT[coln * 65 + rowk] = f2bf(W[(size_t)(r0 + rowk) * DIM + c0 + coln]);
        }
        __syncthreads();
#pragma unroll
        for (int i = 0; i < 2; i++) {
            const int idx = i * 256 + t;           // 0..511
            const int nl = idx >> 3, ch = idx & 7;
            const int n = c0 + nl;
            const int row = n & 127, ntile = n >> 7;
            const int kk = (r0 >> 5) + (ch >> 2);
            const int sw = (ch & 3) ^ ((row ^ (row >> 2)) & 3);
            u16* d = wtImg + (size_t)p * WSZ + ((size_t)(ntile * 16 + kk)) * 4096
                   + row * 32 + (sw << 3);
#pragma unroll
            for (int e = 0; e < 8; e++) d[e] = lT[nl * 65 + ch * 8 + e];
        }
    }
}

// --- proj: all-bf16, DMA-staged, XCD-pinned ---------------------------------
__global__ __launch_bounds__(256) void proj_kernel(
    const u16* __restrict__ xb, const u16* __restrict__ wtImg,
    const float* __restrict__ bq, const float* __restrict__ bk,
    const float* __restrict__ bv,
    u16* __restrict__ qb, u16* __restrict__ kbImg, u16* __restrict__ vtImg)
{
    __shared__ u16 smem[16384];

    const int tid = threadIdx.x;
    const int wave = tid >> 6, lane = tid & 63;
    const int l16 = lane & 15, quad = lane >> 4;
    const int wq = wave >> 1, wn = wave & 1;

    const int id = blockIdx.x;
    const int xcd = id & 7, j = id >> 3;
    const int p = j >> 5, t5 = j & 31;
    int mb, nb;
    if (p < 2) { mb = xcd * 8 + (t5 >> 2); nb = t5 & 3; }
    else       { nb = xcd * 8 + (t5 >> 2); mb = t5 & 3; }

    const u16* Abase = (p < 2) ? xb + (size_t)p * XSZ + (size_t)mb * 16 * 4096
                               : wtImg + (size_t)2 * WSZ + (size_t)mb * 16 * 4096;
    const u16* Bbase = (p < 2) ? wtImg + (size_t)p * WSZ + (size_t)nb * 16 * 4096
                               : xb + (size_t)2 * XSZ + (size_t)nb * 16 * 4096;
    const int doff = tid * 8;

    f32x4 acc[4][4];
#pragma unroll
    for (int ms = 0; ms < 4; ms++)
#pragma unroll
        for (int ns = 0; ns < 4; ns++)
#pragma unroll
            for (int jj = 0; jj < 4; jj++) acc[ms][ns][jj] = 0.f;

#pragma unroll
    for (int e = 0; e < 2; e++) {
        dma16(Abase + e * 2048 + doff, smem + e * 2048 + doff);
        dma16(Bbase + e * 2048 + doff, smem + 4096 + e * 2048 + doff);
    }
    Abase += 4096; Bbase += 4096;

    for (int kt = 0; kt < 16; kt++) {
        __syncthreads();
        if (kt < 15) {
            u16* lb = smem + ((kt + 1) & 1) * 8192;
#pragma unroll
            for (int e = 0; e < 2; e++) {
                dma16(Abase + e * 2048 + doff, lb + e * 2048 + doff);
                dma16(Bbase + e * 2048 + doff, lb + 4096 + e * 2048 + doff);
            }
            Abase += 4096; Bbase += 4096;
        }
        const u16* lA = smem + (kt & 1) * 8192;
        const u16* lB = lA + 4096;

        bf16x8 af[4];
#pragma unroll
        for (int ms = 0; ms < 4; ms++) {
            const int row = wq * 64 + ms * 16 + l16;
            const int sr = (row ^ (row >> 2)) & 3;
            af[ms] = *(const bf16x8*)&lA[row * 32 + ((quad ^ sr) << 3)];
        }
#pragma unroll
        for (int ns = 0; ns < 4; ns++) {
            const int rowb = wn * 64 + ns * 16 + l16;
            const int sb = (rowb ^ (rowb >> 2)) & 3;
            const bf16x8 b = *(const bf16x8*)&lB[rowb * 32 + ((quad ^ sb) << 3)];
#pragma unroll
            for (int ms = 0; ms < 4; ms++)
                acc[ms][ns] = __builtin_amdgcn_mfma_f32_16x16x32_bf16(af[ms], b, acc[ms][ns], 0, 0, 0);
        }
    }

    __syncthreads();
    if (p < 2) {
        const float* bias = p ? bk : bq;
        const float cs = (p == 0) ? 0.18033688011112042f : 1.0f;   // log2e/8
        const int stl = wn * 2 + wq;
        const int hh = nb * 2 + wn;
#pragma unroll
        for (int ns = 0; ns < 4; ns++) {
            const int ch = ns * 16 + l16;
            const float bval = bias[hh * 64 + ch];
#pragma unroll
            for (int ms = 0; ms < 4; ms++)
#pragma unroll
                for (int rr = 0; rr < 4; rr++) {
                    const int sqL = ms * 16 + quad * 4 + rr;
                    const float v = (acc[ms][ns][rr] + bval) * cs;
                    int off;
                    if (p == 0) off = sqL * 64 + ch;
                    else        off = sqL * 64 +
                                      (((ch >> 3) ^ ((sqL ^ (sqL >> 3)) & 7)) << 3) + (ch & 7);
                    smem[stl * 4096 + off] = f2bf(v);
                }
        }
    } else {
        const int stl = wq * 2 + wn;
#pragma unroll
        for (int ms = 0; ms < 4; ms++)
#pragma unroll
            for (int rr = 0; rr < 4; rr++) {
                const int hd = ms * 16 + quad * 4 + rr;
                const float bval = bv[mb * 128 + wq * 64 + hd];
                const int swh = (hd ^ (hd >> 3)) & 7;
#pragma unroll
                for (int ns = 0; ns < 4; ns++) {
                    const int nl = ns * 16 + l16;
                    const int sqpL = (nl & ~12) | ((nl & 8) >> 1) | ((nl & 4) << 1);
                    smem[stl * 4096 + hd * 64 +
                         (((sqpL >> 3) ^ swh) << 3) + (sqpL & 7)] =
                        f2h(acc[ms][ns][rr] + bval);
                }
            }
    }
    __syncthreads();

    {
        u16* dstp; size_t gbase;
        if (p < 2) {
            const int hh = nb * 2 + (wave >> 1);
            const int b2 = mb >> 5;
            const int row0 = (mb * 128 + (wave & 1) * 64) & 4095;
            if (p == 0) { dstp = qb;    gbase = ((size_t)(b2 * NH + hh) * 4096 + row0) * 64; }
            else        { dstp = kbImg; gbase = ((size_t)((b2 * NH + hh) * 64 + (row0 >> 6))) * 4096; }
        } else {
            const int hh = mb * 2 + (wave >> 1);
            const int b2 = nb >> 5;
            const int nblk = (nb & 31) * 2 + (wave & 1);
            dstp = vtImg; gbase = ((size_t)((b2 * NH + hh) * 64 + nblk)) * 4096;
        }
#pragma unroll
        for (int e = 0; e < 8; e++) {
            const u32x4 vv = *(const u32x4*)&smem[wave * 4096 + e * 512 + lane * 8];
            *(u32x4*)(dstp + gbase + e * 512 + lane * 8) = vv;
        }
    }
}

// --- flash attention: 512 threads, 4 wq x 2 kh, pipelined inner loop --------
__global__ __launch_bounds__(512, 4) void attn_kernel(
    const u16* __restrict__ qb, const u16* __restrict__ kbImg,
    const u16* __restrict__ vtImg, float* __restrict__ out)
{
    __shared__ u16 smem[2 * 4 * 4096];   // [buf][kh*2+kv][8KB] = 64KB
    float* cmb = (float*)smem;

    const int tid = threadIdx.x;
    const int wave = tid >> 6, lane = tid & 63;
    const int m31 = lane & 31, h = lane >> 5;
    const int wq = wave >> 1, kh = wave & 1;

    const int blk = blockIdx.x;
    const int xcd = blk & 7, idx = blk >> 3;
    const int bh = xcd * 2 + (idx >> 5);
    const int qt = idx & 31;
    const int qbase = qt * 128 + wq * 32;

    bf16x8 qF[4];
#pragma unroll
    for (int c = 0; c < 4; c++)
        qF[c] = *(const bf16x8*)(qb + ((size_t)bh * SEQ + qbase + m31) * HD + c * 16 + h * 8);

    f32x16 O0, O1;
#pragma unroll
    for (int j = 0; j < 16; j++) { O0[j] = 0.f; O1[j] = 0.f; }
    float la_ = 0.f, lb_ = 0.f;
#if HAVE_FDOT2
    const f16x2 one2 = {(_Float16)1.f, (_Float16)1.f};
#endif

    const int st  = wave >> 1;
    const int hw  = wave & 1;
    const u16* img = (st & 1) ? vtImg : kbImg;
    const u16* gp = img + ((size_t)(bh * 64 + (st >> 1) * 32)) * 4096 + hw * 2048 + lane * 8;
    {
        u16* lb = smem + st * 4096 + hw * 2048 + lane * 8;
#pragma unroll
        for (int e = 0; e < 4; e++) dma16(gp + e * 512, lb + e * 512);
        gp += 4096;
    }

    // loop-invariant swizzle offsets
    const int swV0 = (m31 ^ (m31 >> 3)) & 7;
    const int rV1  = 32 + m31;
    const int swV1 = (rV1 ^ (rV1 >> 3)) & 7;
    const int rK0  = m31;
    const int swK0 = (rK0 ^ (rK0 >> 3)) & 7;
    const int rK1  = 32 + m31;
    const int swK1 = (rK1 ^ (rK1 >> 3)) & 7;

    const int NT = 32;
    for (int it = 0; it < NT; it++) {
        __syncthreads();
        if (it + 1 < NT) {
            u16* lb = smem + ((((it + 1) & 1) * 4 + st)) * 4096 + hw * 2048 + lane * 8;
#pragma unroll
            for (int e = 0; e < 4; e++) dma16(gp + e * 512, lb + e * 512);
            gp += 4096;
        }
        const u16* sK = smem + (size_t)(((it & 1) * 4) + kh * 2) * 4096;
        const u16* sV = sK + 4096;

        // ---- phase 0: kg0 K frags + QK0 ----
        bf16x8 kA0[4];
#pragma unroll
        for (int c = 0; c < 4; c++)
            kA0[c] = *(const bf16x8*)&sK[(rK0 << 6) + (((2 * c + h) ^ swK0) << 3)];

        f32x16 Sv0;
#pragma unroll
        for (int j = 0; j < 16; j++) Sv0[j] = 0.f;
        __builtin_amdgcn_s_setprio(1);
#pragma unroll
        for (int c = 0; c < 4; c++)
            Sv0 = __builtin_amdgcn_mfma_f32_32x32x16_bf16(kA0[c], qF[c], Sv0, 0, 0, 0);
        __builtin_amdgcn_s_setprio(0);

        // kg0 V frags
        f16x8 vA00[2], vA01[2];
#pragma unroll
        for (int c2 = 0; c2 < 2; c2++) {
            vA00[c2] = *(const f16x8*)&sV[(m31 << 6) + (((2 * c2 + h) ^ swV0) << 3)];
            vA01[c2] = *(const f16x8*)&sV[(rV1 << 6) + (((2 * c2 + h) ^ swV1) << 3)];
        }

        // ---- phase 1: exp/pack kg0 ----
        u32 P0[8];
#pragma unroll
        for (int mm = 0; mm < 8; mm++) {
            const float ea = __builtin_amdgcn_exp2f(Sv0[2 * mm]);
            const float eb = __builtin_amdgcn_exp2f(Sv0[2 * mm + 1]);
            P0[mm] = pack_pkrtz(ea, eb);
#if HAVE_FDOT2
            const f16x2 pp = __builtin_bit_cast(f16x2, P0[mm]);
            if (mm & 1) lb_ = __builtin_amdgcn_fdot2(pp, one2, lb_, false);
            else        la_ = __builtin_amdgcn_fdot2(pp, one2, la_, false);
#else
            if (mm & 1) lb_ += ea + eb; else la_ += ea + eb;
#endif
        }
        u32x4 g0, g1;
        g0[0] = P0[0]; g0[1] = P0[1]; g0[2] = P0[2]; g0[3] = P0[3];
        g1[0] = P0[4]; g1[1] = P0[5]; g1[2] = P0[6]; g1[3] = P0[7];
        const f16x8 pf00 = __builtin_bit_cast(f16x8, g0);
        const f16x8 pf01 = __builtin_bit_cast(f16x8, g1);

        // ---- phase 2: kg1 K frags; QK1 interleaved 1:1 with PV0 ----
        bf16x8 kA1[4];
#pragma unroll
        for (int c = 0; c < 4; c++)
            kA1[c] = *(const bf16x8*)&sK[(rK1 << 6) + (((2 * c + h) ^ swK1) << 3)];

        f32x16 Sv1;
#pragma unroll
        for (int j = 0; j < 16; j++) Sv1[j] = 0.f;

        __builtin_amdgcn_s_setprio(1);
        Sv1 = __builtin_amdgcn_mfma_f32_32x32x16_bf16(kA1[0], qF[0], Sv1, 0, 0, 0);
        O0  = __builtin_amdgcn_mfma_f32_32x32x16_f16(vA00[0], pf00, O0, 0, 0, 0);
        Sv1 = __builtin_amdgcn_mfma_f32_32x32x16_bf16(kA1[1], qF[1], Sv1, 0, 0, 0);
        O0  = __builtin_amdgcn_mfma_f32_32x32x16_f16(vA00[1], pf01, O0, 0, 0, 0);
        Sv1 = __builtin_amdgcn_mfma_f32_32x32x16_bf16(kA1[2], qF[2], Sv1, 0, 0, 0);
        O1  = __builtin_amdgcn_mfma_f32_32x32x16_f16(vA01[0], pf00, O1, 0, 0, 0);
        Sv1 = __builtin_amdgcn_mfma_f32_32x32x16_bf16(kA1[3], qF[3], Sv1, 0, 0, 0);
        O1  = __builtin_amdgcn_mfma_f32_32x32x16_f16(vA01[1], pf01, O1, 0, 0, 0);
        __builtin_amdgcn_s_setprio(0);

        // kg1 V frags
        f16x8 vA10[2], vA11[2];
#pragma unroll
        for (int c2 = 0; c2 < 2; c2++) {
            vA10[c2] = *(const f16x8*)&sV[(m31 << 6) + (((4 + 2 * c2 + h) ^ swV0) << 3)];
            vA11[c2] = *(const f16x8*)&sV[(rV1 << 6) + (((4 + 2 * c2 + h) ^ swV1) << 3)];
        }

        // ---- phase 3: exp/pack kg1 ----
        u32 P1[8];
#pragma unroll
        for (int mm = 0; mm < 8; mm++) {
            const float ea = __builtin_amdgcn_exp2f(Sv1[2 * mm]);
            const float eb = __builtin_amdgcn_exp2f(Sv1[2 * mm + 1]);
            P1[mm] = pack_pkrtz(ea, eb);
#if HAVE_FDOT2
            const f16x2 pp = __builtin_bit_cast(f16x2, P1[mm]);
            if (mm & 1) lb_ = __builtin_amdgcn_fdot2(pp, one2, lb_, false);
            else        la_ = __builtin_amdgcn_fdot2(pp, one2, la_, false);
#else
            if (mm & 1) lb_ += ea + eb; else la_ += ea + eb;
#endif
        }
        u32x4 h0, h1;
        h0[0] = P1[0]; h0[1] = P1[1]; h0[2] = P1[2]; h0[3] = P1[3];
        h1[0] = P1[4]; h1[1] = P1[5]; h1[2] = P1[6]; h1[3] = P1[7];
        const f16x8 pf10 = __builtin_bit_cast(f16x8, h0);
        const f16x8 pf11 = __builtin_bit_cast(f16x8, h1);

        // ---- phase 4: PV1 ----
        __builtin_amdgcn_s_setprio(1);
        O0 = __builtin_amdgcn_mfma_f32_32x32x16_f16(vA10[0], pf10, O0, 0, 0, 0);
        O0 = __builtin_amdgcn_mfma_f32_32x32x16_f16(vA10[1], pf11, O0, 0, 0, 0);
        O1 = __builtin_amdgcn_mfma_f32_32x32x16_f16(vA11[0], pf10, O1, 0, 0, 0);
        O1 = __builtin_amdgcn_mfma_f32_32x32x16_f16(vA11[1], pf11, O1, 0, 0, 0);
        __builtin_amdgcn_s_setprio(0);
    }

    float l_acc = la_ + lb_;
    l_acc += __shfl_xor(l_acc, 32);
    __syncthreads();
    if (kh == 1) {
#pragma unroll
        for (int hg = 0; hg < 2; hg++)
#pragma unroll
            for (int mm = 0; mm < 4; mm++) {
                f32x4 o;
#pragma unroll
                for (int j = 0; j < 4; j++) o[j] = (hg ? O1 : O0)[4 * mm + j];
                *(f32x4*)&cmb[(((wq * 2 + hg) * 4 + mm) << 8) + lane * 4] = o;
            }
        cmb[8192 + wq * 64 + lane] = l_acc;
    }
    __syncthreads();

    if (kh == 0) {
        const int b = bh >> 3, hcol = bh & 7;
        const float lt = l_acc + cmb[8192 + wq * 64 + lane];
        const float inv = 1.0f / lt;
        const int sq = qbase + m31;
#pragma unroll
        for (int hg = 0; hg < 2; hg++)
#pragma unroll
            for (int mm = 0; mm < 4; mm++) {
                const f32x4 po = *(const f32x4*)&cmb[(((wq * 2 + hg) * 4 + mm) << 8) + lane * 4];
                f32x4 o;
#pragma unroll
                for (int j = 0; j < 4; j++)
                    o[j] = ((hg ? O1 : O0)[4 * mm + j] + po[j]) * inv;
                *(f32x4*)&out[(((size_t)(b * SEQ + sq)) << 9) + hcol * 64
                              + hg * 32 + 8 * mm + 4 * h] = o;
            }
    }
}

// ---------------------------------------------------------------------------
extern "C" void kernel_launch(void* const* d_in, const int* in_sizes, int n_in,
                              void* d_out, int out_size, void* d_ws, size_t ws_size,
                              hipStream_t stream)
{
    const float* q  = (const float*)d_in[0];
    const float* k  = (const float*)d_in[1];
    const float* v  = (const float*)d_in[2];
    const float* Wq = (const float*)d_in[3];
    const float* bq = (const float*)d_in[4];
    const float* Wk = (const float*)d_in[5];
    const float* bk = (const float*)d_in[6];
    const float* Wv = (const float*)d_in[7];
    const float* bv = (const float*)d_in[8];
    float* out = (float*)d_out;

    // ws layout (u16): xb[3*XSZ] | wtImg[3*WSZ] | qb[QSZ] | kbImg[QSZ] | vtImg[QSZ]
    u16* xb  = (u16*)d_ws;
    u16* wti = xb  + (size_t)3 * XSZ;
    u16* qbp = wti + (size_t)3 * WSZ;
    u16* kbp = qbp + (size_t)QSZ;
    u16* vtp = kbp + (size_t)QSZ;

    prep_kernel<<<dim3(3264), 256, 0, stream>>>(q, k, v, Wq, Wk, Wv, xb, wti);
    proj_kernel<<<dim3(768),  256, 0, stream>>>(xb, wti, bq, bk, bv,
                                                qbp, kbp, vtp);
    attn_kernel<<<dim3(512),  512, 0, stream>>>(qbp, kbp, vtp, out);
}

// Round 3
// 201.764 us; speedup vs baseline: 3.8250x; 1.0037x over previous
//
#include <hip/hip_runtime.h>
#include <hip/hip_bf16.h>
#include <cstdint>

// ---------------------------------------------------------------------------
// B=2, S=4096, D=512, H=8, HD=64.
// wt:   W -> W^T bf16 proj-image (tiny, 192 blocks).
// proj: fused X-conversion GEMM. X fp32 is loaded directly (coalesced),
//       converted to bf16 in registers and ds_written into the LDS slab
//       image layout (byte-identical to the old xb DMA path). W-side stays
//       global_load_lds. Eliminates the xb image round-trip entirely
//       (~75 MB HBM + one kernel launch).
// attn: byte-identical to round 2 (512 thr, 4wq x 2kh, pipelined
//       QK1<->PV0 inner loop, fdot2 l-sum, setprio). 80 us measured.
// ---------------------------------------------------------------------------

typedef __bf16   bf16x8 __attribute__((ext_vector_type(8)));
typedef _Float16 f16x8  __attribute__((ext_vector_type(8)));
typedef _Float16 f16x2  __attribute__((ext_vector_type(2)));
typedef float    f32x4  __attribute__((ext_vector_type(4)));
typedef float    f32x16 __attribute__((ext_vector_type(16)));
typedef unsigned int   u32;
typedef unsigned int   u32x4 __attribute__((ext_vector_type(4)));
typedef unsigned short u16;

#define NB  2
#define SEQ 4096
#define DIM 512
#define NH  8
#define HD  64
#define WSZ (DIM * DIM)
#define QSZ (NB * NH * SEQ * HD)

#if __has_builtin(__builtin_amdgcn_fdot2)
#define HAVE_FDOT2 1
#else
#define HAVE_FDOT2 0
#endif

__device__ __forceinline__ u16 f2bf(float f) {
    __bf16 h = (__bf16)f; return __builtin_bit_cast(u16, h);
}
__device__ __forceinline__ u16 f2h(float f) {
    _Float16 h = (_Float16)f; return __builtin_bit_cast(u16, h);
}
__device__ __forceinline__ u32 pack_pkrtz(float a, float b) {
    auto pk = __builtin_amdgcn_cvt_pkrtz(a, b);
    return __builtin_bit_cast(u32, pk);
}
__device__ __forceinline__ bf16x8 cvt8p(float4 a, float4 b) {
    bf16x8 o;
    o[0]=(__bf16)a.x; o[1]=(__bf16)a.y; o[2]=(__bf16)a.z; o[3]=(__bf16)a.w;
    o[4]=(__bf16)b.x; o[5]=(__bf16)b.y; o[6]=(__bf16)b.z; o[7]=(__bf16)b.w;
    return o;
}
__device__ __forceinline__ void dma16(const u16* g, u16* l) {
    __builtin_amdgcn_global_load_lds(
        (const __attribute__((address_space(1))) u32*)g,
        (__attribute__((address_space(3))) u32*)l, 16, 0, 0);
}

// --- wt: W^T bf16 proj-image ------------------------------------------------
__global__ __launch_bounds__(256) void wt_kernel(
    const float* __restrict__ Wq, const float* __restrict__ Wk,
    const float* __restrict__ Wv, u16* __restrict__ wtImg)
{
    __shared__ u16 lT[64 * 65];
    const int p = blockIdx.z;
    const float* W = (p == 0) ? Wq : ((p == 1) ? Wk : Wv);
    const int r0 = blockIdx.x * 64, c0 = blockIdx.y * 64;   // r0 = k, c0 = n
    const int t = threadIdx.x;
#pragma unroll
    for (int i = 0; i < 16; i++) {
        int idx = i * 256 + t, rowk = idx >> 6, coln = idx & 63;
        lT[coln * 65 + rowk] = f2bf(W[(size_t)(r0 + rowk) * DIM + c0 + coln]);
    }
    __syncthreads();
#pragma unroll
    for (int i = 0; i < 2; i++) {
        const int idx = i * 256 + t;           // 0..511
        const int nl = idx >> 3, ch = idx & 7;
        const int n = c0 + nl;
        const int row = n & 127, ntile = n >> 7;
        const int kk = (r0 >> 5) + (ch >> 2);
        const int sw = (ch & 3) ^ ((row ^ (row >> 2)) & 3);
        u16* d = wtImg + (size_t)p * WSZ + ((size_t)(ntile * 16 + kk)) * 4096
               + row * 32 + (sw << 3);
#pragma unroll
        for (int e = 0; e < 8; e++) d[e] = lT[nl * 65 + ch * 8 + e];
    }
}

// --- proj: fused X-cvt GEMM, W-side DMA, XCD-pinned -------------------------
__global__ __launch_bounds__(256) void proj_kernel(
    const float* __restrict__ xq, const float* __restrict__ xk,
    const float* __restrict__ xv, const u16* __restrict__ wtImg,
    const float* __restrict__ bq, const float* __restrict__ bk,
    const float* __restrict__ bv,
    u16* __restrict__ qb, u16* __restrict__ kbImg, u16* __restrict__ vtImg)
{
    __shared__ u16 smem[16384];   // 2 x (A 4096 | B 4096) u16; epilogue tile

    const int tid = threadIdx.x;
    const int wave = tid >> 6, lane = tid & 63;
    const int l16 = lane & 15, quad = lane >> 4;
    const int wq = wave >> 1, wn = wave & 1;

    const int id = blockIdx.x;
    const int xcd = id & 7, j = id >> 3;
    const int p = j >> 5, t5 = j & 31;
    int mb, nb;
    if (p < 2) { mb = xcd * 8 + (t5 >> 2); nb = t5 & 3; }
    else       { nb = xcd * 8 + (t5 >> 2); mb = t5 & 3; }

    // X side (fp32 direct): A half for p<2, B half for p==2.
    const float* Xp = (p == 0) ? xq : ((p == 1) ? xk : xv);
    const int xtile = (p < 2) ? mb : nb;
    const int row = tid >> 1, half = tid & 1;
    const int sr = (row ^ (row >> 2)) & 3;
    const float* xsrc = Xp + (size_t)(xtile * 128 + row) * DIM + half * 16;
    const int xldsoff = (p < 2) ? 0 : 4096;       // u16 units within a buffer
    const int c0 = (((half * 2) ^ sr) << 3), c1 = (((half * 2 + 1) ^ sr) << 3);

    // W side (bf16 image, global_load_lds): B half for p<2, A half for p==2.
    const u16* Wbase = (p < 2) ? wtImg + (size_t)p * WSZ + (size_t)nb * 16 * 4096
                               : wtImg + (size_t)2 * WSZ + (size_t)mb * 16 * 4096;
    const int wldsoff = (p < 2) ? 4096 : 0;
    const int doff = tid * 8;   // u16 units; 16B per thread per dma

    f32x4 acc[4][4];
#pragma unroll
    for (int ms = 0; ms < 4; ms++)
#pragma unroll
        for (int ns = 0; ns < 4; ns++)
#pragma unroll
            for (int jj = 0; jj < 4; jj++) acc[ms][ns][jj] = 0.f;

    // prologue: slab 0 -> buf 0 (W via DMA, X via reg-cvt)
    {
        float4 a0 = ((const float4*)xsrc)[0], a1 = ((const float4*)xsrc)[1];
        float4 a2 = ((const float4*)xsrc)[2], a3 = ((const float4*)xsrc)[3];
        xsrc += 32;
#pragma unroll
        for (int e = 0; e < 2; e++)
            dma16(Wbase + e * 2048 + doff, smem + wldsoff + e * 2048 + doff);
        Wbase += 4096;
        u16* xd = smem + xldsoff + row * 32;
        *(bf16x8*)(xd + c0) = cvt8p(a0, a1);
        *(bf16x8*)(xd + c1) = cvt8p(a2, a3);
    }

    for (int kt = 0; kt < 16; kt++) {
        __syncthreads();
        float4 a0, a1, a2, a3;
        if (kt < 15) {
            u16* buf = smem + ((kt + 1) & 1) * 8192;
#pragma unroll
            for (int e = 0; e < 2; e++)
                dma16(Wbase + e * 2048 + doff, buf + wldsoff + e * 2048 + doff);
            Wbase += 4096;
            a0 = ((const float4*)xsrc)[0]; a1 = ((const float4*)xsrc)[1];
            a2 = ((const float4*)xsrc)[2]; a3 = ((const float4*)xsrc)[3];
            xsrc += 32;
        }
        const u16* lA = smem + (kt & 1) * 8192;
        const u16* lB = lA + 4096;

        bf16x8 af[4];
#pragma unroll
        for (int ms = 0; ms < 4; ms++) {
            const int rowa = wq * 64 + ms * 16 + l16;
            const int sra = (rowa ^ (rowa >> 2)) & 3;
            af[ms] = *(const bf16x8*)&lA[rowa * 32 + ((quad ^ sra) << 3)];
        }
#pragma unroll
        for (int ns = 0; ns < 4; ns++) {
            const int rowb = wn * 64 + ns * 16 + l16;
            const int sb = (rowb ^ (rowb >> 2)) & 3;
            const bf16x8 b = *(const bf16x8*)&lB[rowb * 32 + ((quad ^ sb) << 3)];
#pragma unroll
            for (int ms = 0; ms < 4; ms++)
                acc[ms][ns] = __builtin_amdgcn_mfma_f32_16x16x32_bf16(af[ms], b, acc[ms][ns], 0, 0, 0);
        }

        if (kt < 15) {
            u16* xd = smem + ((kt + 1) & 1) * 8192 + xldsoff + row * 32;
            *(bf16x8*)(xd + c0) = cvt8p(a0, a1);
            *(bf16x8*)(xd + c1) = cvt8p(a2, a3);
        }
    }

    // ---- epilogue: stage tile in LDS in output-image order, dump linearly ---
    __syncthreads();
    if (p < 2) {
        const float* bias = p ? bk : bq;
        const float cs = (p == 0) ? 0.18033688011112042f : 1.0f;   // log2e/8
        const int stl = wn * 2 + wq;
        const int hh = nb * 2 + wn;
#pragma unroll
        for (int ns = 0; ns < 4; ns++) {
            const int ch = ns * 16 + l16;
            const float bval = bias[hh * 64 + ch];
#pragma unroll
            for (int ms = 0; ms < 4; ms++)
#pragma unroll
                for (int rr = 0; rr < 4; rr++) {
                    const int sqL = ms * 16 + quad * 4 + rr;
                    const float v = (acc[ms][ns][rr] + bval) * cs;
                    int off;
                    if (p == 0) off = sqL * 64 + ch;
                    else        off = sqL * 64 +
                                      (((ch >> 3) ^ ((sqL ^ (sqL >> 3)) & 7)) << 3) + (ch & 7);
                    smem[stl * 4096 + off] = f2bf(v);
                }
        }
    } else {
        const int stl = wq * 2 + wn;
#pragma unroll
        for (int ms = 0; ms < 4; ms++)
#pragma unroll
            for (int rr = 0; rr < 4; rr++) {
                const int hd = ms * 16 + quad * 4 + rr;
                const float bval = bv[mb * 128 + wq * 64 + hd];
                const int swh = (hd ^ (hd >> 3)) & 7;
#pragma unroll
                for (int ns = 0; ns < 4; ns++) {
                    const int nl = ns * 16 + l16;
                    const int sqpL = (nl & ~12) | ((nl & 8) >> 1) | ((nl & 4) << 1);
                    smem[stl * 4096 + hd * 64 +
                         (((sqpL >> 3) ^ swh) << 3) + (sqpL & 7)] =
                        f2h(acc[ms][ns][rr] + bval);
                }
            }
    }
    __syncthreads();

    {
        u16* dstp; size_t gbase;
        if (p < 2) {
            const int hh = nb * 2 + (wave >> 1);
            const int b2 = mb >> 5;
            const int row0 = (mb * 128 + (wave & 1) * 64) & 4095;
            if (p == 0) { dstp = qb;    gbase = ((size_t)(b2 * NH + hh) * 4096 + row0) * 64; }
            else        { dstp = kbImg; gbase = ((size_t)((b2 * NH + hh) * 64 + (row0 >> 6))) * 4096; }
        } else {
            const int hh = mb * 2 + (wave >> 1);
            const int b2 = nb >> 5;
            const int nblk = (nb & 31) * 2 + (wave & 1);
            dstp = vtImg; gbase = ((size_t)((b2 * NH + hh) * 64 + nblk)) * 4096;
        }
#pragma unroll
        for (int e = 0; e < 8; e++) {
            const u32x4 vv = *(const u32x4*)&smem[wave * 4096 + e * 512 + lane * 8];
            *(u32x4*)(dstp + gbase + e * 512 + lane * 8) = vv;
        }
    }
}

// --- flash attention: 512 threads, 4 wq x 2 kh, pipelined inner loop --------
__global__ __launch_bounds__(512, 4) void attn_kernel(
    const u16* __restrict__ qb, const u16* __restrict__ kbImg,
    const u16* __restrict__ vtImg, float* __restrict__ out)
{
    __shared__ u16 smem[2 * 4 * 4096];   // [buf][kh*2+kv][8KB] = 64KB
    float* cmb = (float*)smem;

    const int tid = threadIdx.x;
    const int wave = tid >> 6, lane = tid & 63;
    const int m31 = lane & 31, h = lane >> 5;
    const int wq = wave >> 1, kh = wave & 1;

    const int blk = blockIdx.x;
    const int xcd = blk & 7, idx = blk >> 3;
    const int bh = xcd * 2 + (idx >> 5);
    const int qt = idx & 31;
    const int qbase = qt * 128 + wq * 32;

    bf16x8 qF[4];
#pragma unroll
    for (int c = 0; c < 4; c++)
        qF[c] = *(const bf16x8*)(qb + ((size_t)bh * SEQ + qbase + m31) * HD + c * 16 + h * 8);

    f32x16 O0, O1;
#pragma unroll
    for (int j = 0; j < 16; j++) { O0[j] = 0.f; O1[j] = 0.f; }
    float la_ = 0.f, lb_ = 0.f;
#if HAVE_FDOT2
    const f16x2 one2 = {(_Float16)1.f, (_Float16)1.f};
#endif

    const int st  = wave >> 1;
    const int hw  = wave & 1;
    const u16* img = (st & 1) ? vtImg : kbImg;
    const u16* gp = img + ((size_t)(bh * 64 + (st >> 1) * 32)) * 4096 + hw * 2048 + lane * 8;
    {
        u16* lb = smem + st * 4096 + hw * 2048 + lane * 8;
#pragma unroll
        for (int e = 0; e < 4; e++) dma16(gp + e * 512, lb + e * 512);
        gp += 4096;
    }

    // loop-invariant swizzle offsets
    const int swV0 = (m31 ^ (m31 >> 3)) & 7;
    const int rV1  = 32 + m31;
    const int swV1 = (rV1 ^ (rV1 >> 3)) & 7;
    const int rK0  = m31;
    const int swK0 = (rK0 ^ (rK0 >> 3)) & 7;
    const int rK1  = 32 + m31;
    const int swK1 = (rK1 ^ (rK1 >> 3)) & 7;

    const int NT = 32;
    for (int it = 0; it < NT; it++) {
        __syncthreads();
        if (it + 1 < NT) {
            u16* lb = smem + ((((it + 1) & 1) * 4 + st)) * 4096 + hw * 2048 + lane * 8;
#pragma unroll
            for (int e = 0; e < 4; e++) dma16(gp + e * 512, lb + e * 512);
            gp += 4096;
        }
        const u16* sK = smem + (size_t)(((it & 1) * 4) + kh * 2) * 4096;
        const u16* sV = sK + 4096;

        // ---- phase 0: kg0 K frags + QK0 ----
        bf16x8 kA0[4];
#pragma unroll
        for (int c = 0; c < 4; c++)
            kA0[c] = *(const bf16x8*)&sK[(rK0 << 6) + (((2 * c + h) ^ swK0) << 3)];

        f32x16 Sv0;
#pragma unroll
        for (int j = 0; j < 16; j++) Sv0[j] = 0.f;
        __builtin_amdgcn_s_setprio(1);
#pragma unroll
        for (int c = 0; c < 4; c++)
            Sv0 = __builtin_amdgcn_mfma_f32_32x32x16_bf16(kA0[c], qF[c], Sv0, 0, 0, 0);
        __builtin_amdgcn_s_setprio(0);

        // kg0 V frags
        f16x8 vA00[2], vA01[2];
#pragma unroll
        for (int c2 = 0; c2 < 2; c2++) {
            vA00[c2] = *(const f16x8*)&sV[(m31 << 6) + (((2 * c2 + h) ^ swV0) << 3)];
            vA01[c2] = *(const f16x8*)&sV[(rV1 << 6) + (((2 * c2 + h) ^ swV1) << 3)];
        }

        // ---- phase 1: exp/pack kg0 ----
        u32 P0[8];
#pragma unroll
        for (int mm = 0; mm < 8; mm++) {
            const float ea = __builtin_amdgcn_exp2f(Sv0[2 * mm]);
            const float eb = __builtin_amdgcn_exp2f(Sv0[2 * mm + 1]);
            P0[mm] = pack_pkrtz(ea, eb);
#if HAVE_FDOT2
            const f16x2 pp = __builtin_bit_cast(f16x2, P0[mm]);
            if (mm & 1) lb_ = __builtin_amdgcn_fdot2(pp, one2, lb_, false);
            else        la_ = __builtin_amdgcn_fdot2(pp, one2, la_, false);
#else
            if (mm & 1) lb_ += ea + eb; else la_ += ea + eb;
#endif
        }
        u32x4 g0, g1;
        g0[0] = P0[0]; g0[1] = P0[1]; g0[2] = P0[2]; g0[3] = P0[3];
        g1[0] = P0[4]; g1[1] = P0[5]; g1[2] = P0[6]; g1[3] = P0[7];
        const f16x8 pf00 = __builtin_bit_cast(f16x8, g0);
        const f16x8 pf01 = __builtin_bit_cast(f16x8, g1);

        // ---- phase 2: kg1 K frags; QK1 interleaved 1:1 with PV0 ----
        bf16x8 kA1[4];
#pragma unroll
        for (int c = 0; c < 4; c++)
            kA1[c] = *(const bf16x8*)&sK[(rK1 << 6) + (((2 * c + h) ^ swK1) << 3)];

        f32x16 Sv1;
#pragma unroll
        for (int j = 0; j < 16; j++) Sv1[j] = 0.f;

        __builtin_amdgcn_s_setprio(1);
        Sv1 = __builtin_amdgcn_mfma_f32_32x32x16_bf16(kA1[0], qF[0], Sv1, 0, 0, 0);
        O0  = __builtin_amdgcn_mfma_f32_32x32x16_f16(vA00[0], pf00, O0, 0, 0, 0);
        Sv1 = __builtin_amdgcn_mfma_f32_32x32x16_bf16(kA1[1], qF[1], Sv1, 0, 0, 0);
        O0  = __builtin_amdgcn_mfma_f32_32x32x16_f16(vA00[1], pf01, O0, 0, 0, 0);
        Sv1 = __builtin_amdgcn_mfma_f32_32x32x16_bf16(kA1[2], qF[2], Sv1, 0, 0, 0);
        O1  = __builtin_amdgcn_mfma_f32_32x32x16_f16(vA01[0], pf00, O1, 0, 0, 0);
        Sv1 = __builtin_amdgcn_mfma_f32_32x32x16_bf16(kA1[3], qF[3], Sv1, 0, 0, 0);
        O1  = __builtin_amdgcn_mfma_f32_32x32x16_f16(vA01[1], pf01, O1, 0, 0, 0);
        __builtin_amdgcn_s_setprio(0);

        // kg1 V frags
        f16x8 vA10[2], vA11[2];
#pragma unroll
        for (int c2 = 0; c2 < 2; c2++) {
            vA10[c2] = *(const f16x8*)&sV[(m31 << 6) + (((4 + 2 * c2 + h) ^ swV0) << 3)];
            vA11[c2] = *(const f16x8*)&sV[(rV1 << 6) + (((4 + 2 * c2 + h) ^ swV1) << 3)];
        }

        // ---- phase 3: exp/pack kg1 ----
        u32 P1[8];
#pragma unroll
        for (int mm = 0; mm < 8; mm++) {
            const float ea = __builtin_amdgcn_exp2f(Sv1[2 * mm]);
            const float eb = __builtin_amdgcn_exp2f(Sv1[2 * mm + 1]);
            P1[mm] = pack_pkrtz(ea, eb);
#if HAVE_FDOT2
            const f16x2 pp = __builtin_bit_cast(f16x2, P1[mm]);
            if (mm & 1) lb_ = __builtin_amdgcn_fdot2(pp, one2, lb_, false);
            else        la_ = __builtin_amdgcn_fdot2(pp, one2, la_, false);
#else
            if (mm & 1) lb_ += ea + eb; else la_ += ea + eb;
#endif
        }
        u32x4 h0, h1;
        h0[0] = P1[0]; h0[1] = P1[1]; h0[2] = P1[2]; h0[3] = P1[3];
        h1[0] = P1[4]; h1[1] = P1[5]; h1[2] = P1[6]; h1[3] = P1[7];
        const f16x8 pf10 = __builtin_bit_cast(f16x8, h0);
        const f16x8 pf11 = __builtin_bit_cast(f16x8, h1);

        // ---- phase 4: PV1 ----
        __builtin_amdgcn_s_setprio(1);
        O0 = __builtin_amdgcn_mfma_f32_32x32x16_f16(vA10[0], pf10, O0, 0, 0, 0);
        O0 = __builtin_amdgcn_mfma_f32_32x32x16_f16(vA10[1], pf11, O0, 0, 0, 0);
        O1 = __builtin_amdgcn_mfma_f32_32x32x16_f16(vA11[0], pf10, O1, 0, 0, 0);
        O1 = __builtin_amdgcn_mfma_f32_32x32x16_f16(vA11[1], pf11, O1, 0, 0, 0);
        __builtin_amdgcn_s_setprio(0);
    }

    float l_acc = la_ + lb_;
    l_acc += __shfl_xor(l_acc, 32);
    __syncthreads();
    if (kh == 1) {
#pragma unroll
        for (int hg = 0; hg < 2; hg++)
#pragma unroll
            for (int mm = 0; mm < 4; mm++) {
                f32x4 o;
#pragma unroll
                for (int j = 0; j < 4; j++) o[j] = (hg ? O1 : O0)[4 * mm + j];
                *(f32x4*)&cmb[(((wq * 2 + hg) * 4 + mm) << 8) + lane * 4] = o;
            }
        cmb[8192 + wq * 64 + lane] = l_acc;
    }
    __syncthreads();

    if (kh == 0) {
        const int b = bh >> 3, hcol = bh & 7;
        const float lt = l_acc + cmb[8192 + wq * 64 + lane];
        const float inv = 1.0f / lt;
        const int sq = qbase + m31;
#pragma unroll
        for (int hg = 0; hg < 2; hg++)
#pragma unroll
            for (int mm = 0; mm < 4; mm++) {
                const f32x4 po = *(const f32x4*)&cmb[(((wq * 2 + hg) * 4 + mm) << 8) + lane * 4];
                f32x4 o;
#pragma unroll
                for (int j = 0; j < 4; j++)
                    o[j] = ((hg ? O1 : O0)[4 * mm + j] + po[j]) * inv;
                *(f32x4*)&out[(((size_t)(b * SEQ + sq)) << 9) + hcol * 64
                              + hg * 32 + 8 * mm + 4 * h] = o;
            }
    }
}

// ---------------------------------------------------------------------------
extern "C" void kernel_launch(void* const* d_in, const int* in_sizes, int n_in,
                              void* d_out, int out_size, void* d_ws, size_t ws_size,
                              hipStream_t stream)
{
    const float* q  = (const float*)d_in[0];
    const float* k  = (const float*)d_in[1];
    const float* v  = (const float*)d_in[2];
    const float* Wq = (const float*)d_in[3];
    const float* bq = (const float*)d_in[4];
    const float* Wk = (const float*)d_in[5];
    const float* bk = (const float*)d_in[6];
    const float* Wv = (const float*)d_in[7];
    const float* bv = (const float*)d_in[8];
    float* out = (float*)d_out;

    // ws layout (u16): wtImg[3*WSZ] | qb[QSZ] | kbImg[QSZ] | vtImg[QSZ]
    u16* wti = (u16*)d_ws;
    u16* qbp = wti + (size_t)3 * WSZ;
    u16* kbp = qbp + (size_t)QSZ;
    u16* vtp = kbp + (size_t)QSZ;

    wt_kernel  <<<dim3(8, 8, 3), 256, 0, stream>>>(Wq, Wk, Wv, wti);
    proj_kernel<<<dim3(768),     256, 0, stream>>>(q, k, v, wti, bq, bk, bv,
                                                   qbp, kbp, vtp);
    attn_kernel<<<dim3(512),     512, 0, stream>>>(qbp, kbp, vtp, out);
}